// Round 1
// baseline (251.875 us; speedup 1.0000x reference)
//
#include <hip/hip_runtime.h>

#define TSTEPS 15
#define HID    64
#define LAT    16
#define NBATCH 65536
#define LOG2E  1.44269504088896f

typedef _Float16 v8h __attribute__((ext_vector_type(8)));
typedef _Float16 v4h __attribute__((ext_vector_type(4)));
typedef _Float16 v2h __attribute__((ext_vector_type(2)));
typedef float    v4f __attribute__((ext_vector_type(4)));

__device__ __forceinline__ v8h vzero8() {
    v8h v;
#pragma unroll
    for (int i = 0; i < 8; ++i) v[i] = (_Float16)0.0f;
    return v;
}

// v_cvt_pkrtz returns __fp16x2; bit-cast to our _Float16x2 (same bits).
__device__ __forceinline__ v4h pack4(float a, float b, float c, float d) {
    const v2h lo = __builtin_bit_cast(v2h, __builtin_amdgcn_cvt_pkrtz(a, b));
    const v2h hi = __builtin_bit_cast(v2h, __builtin_amdgcn_cvt_pkrtz(c, d));
    return __builtin_shufflevector(lo, hi, 0, 1, 2, 3);
}

// LSTM cell update with shared-rcp activations. Gate pre-acts ai/af/ag/ao
// arrive PRE-SCALED by log2e (folded into staged weights/biases), so
// exp2(-x) needs no multiply (neg is a free src modifier).
//   sig(a)*tanh(b) = (1-e2)*rcp((1+e1)(1+e2)),  e1=exp2(-a'), e2=exp2(-2b')
__device__ __forceinline__ float cell_update(float ai, float af, float ag,
                                             float ao, float& cst) {
    const float ei = __builtin_amdgcn_exp2f(-ai);
    const float ef = __builtin_amdgcn_exp2f(-af);
    const float eg = __builtin_amdgcn_exp2f(-2.0f * ag);
    const float eo = __builtin_amdgcn_exp2f(-ao);
    const float ig = (1.0f - eg) *
        __builtin_amdgcn_rcpf((1.0f + ei) * (1.0f + eg));      // i*g
    const float f  = __builtin_amdgcn_rcpf(1.0f + ef);          // forget gate
    const float cc = fmaf(f, cst, ig);
    cst = cc;
    const float ec = __builtin_amdgcn_exp2f(cc * (-2.0f * LOG2E));  // true scale
    return (1.0f - ec) *
        __builtin_amdgcn_rcpf((1.0f + eo) * (1.0f + ec));      // o*tanh(c)
}

// Round 14: batch-pair A-fragment reuse.
// Previous structure (16 waves x 16 batch) read every weight A-fragment from
// LDS once PER MFMA: 112 ds_read_b128/wave/t -> ~27.5 MB/CU of LDS reads over
// the kernel (~65% of the LDS read pipe at m134's 85 B/cyc) -- the top pipe.
// Now each wave owns 32 batch columns (two 16-wide N tiles): every A-fragment
// read feeds TWO MFMAs -> A-read traffic per unit of work HALVES.
// Block = 8 waves x 32 batch = 256 batch (grid stays 256 = 1 block/CU);
// 2 waves/SIMD @ 256-reg unified budget (amdgpu_waves_per_eu(2,2)).
// Lost TLP is compensated by 2x within-wave ILP (8 independent cell_update
// chains per a-group, paired MFMAs per A-frag).
//
// LOAD-BEARING (round 7): without the per-iteration asm memory clobber,
// LICM hoists all A-fragment ds_reads out of the t-loop -> forced scratch
// spill -> GBs of HBM scratch traffic. DO NOT REMOVE.
// (Pre-loop register loads are SSA values and survive the clobber.)
//
// Merged steady-state body (one BB): L0(tt) + L1(tt-1). Per-wave LDS
// state machine: write h0(tt) -> read hf -> write h1(tt-1) -> read gf -> FC.
//
//   D[m=gate(256), n=batch(16x2)] = A[weights*log2e] * B[z | h0 | x | h1]
// wf planes: 0=Wih0(z,K16; k=16 -> bias; rest 0) 1,2=Whh0 3,4=Wih1 5,6=Whh1.
// Gate order (PyTorch): 0=i,1=f,2=g,3=o ; g = 64*type + u, u=16a+4q+r;
// acc[ty] -> ty IS the gate type (mt = 4*ty+a).
__global__ __launch_bounds__(512)
__attribute__((amdgpu_waves_per_eu(2, 2)))
void lstm2_pipe5(
        const float* __restrict__ z,
        const float* __restrict__ Wih0, const float* __restrict__ Whh0,
        const float* __restrict__ bih0, const float* __restrict__ bhh0,
        const float* __restrict__ Wih1, const float* __restrict__ Whh1,
        const float* __restrict__ bih1, const float* __restrict__ bhh1,
        const float* __restrict__ Wfc,  const float* __restrict__ bfc,
        float* __restrict__ out)
{
    __shared__ __align__(16) _Float16 wf[7 * 16 * 64 * 8];   // 114688 B
    __shared__ __align__(16) _Float16 wfcf[2 * 64 * 8];      //   2048 B
    __shared__ __align__(16) float    bsum1[256];            //   1024 B
    __shared__ __align__(16) _Float16 state[8][32 * 72];     //  36864 B
                                                             // 154624 B total

    const int tid  = threadIdx.x;
    const int wave = tid >> 6;           // 0..7
    const int lane = tid & 63;
    const int q    = lane >> 4;          // quad
    const int c    = lane & 15;          // batch col within group
    const int row0 = blockIdx.x * 256 + wave * 32;   // wave's batch base

    /* ------- one-time staging: weights + biases, all scaled by log2e ----- */
#pragma unroll 2
    for (int e = tid; e < 7 * 16 * 64 * 8; e += 512) {
        const int j  = e & 7;
        const int lm = (e >> 3) & 63;
        const int mt = (e >> 9) & 15;
        const int p  = e >> 13;                  // fragment plane 0..6
        const int g  = mt * 16 + (lm & 15);      // gate row 0..255
        const int kk = (lm >> 4) * 8 + j;        // k within 32-chunk
        float v;
        if (p == 0)      v = (kk < LAT) ? Wih0[g * LAT + kk]
                           : (kk == LAT ? bih0[g] + bhh0[g] : 0.0f);
        else if (p == 1) v = Whh0[g * HID + kk];
        else if (p == 2) v = Whh0[g * HID + 32 + kk];
        else if (p == 3) v = Wih1[g * HID + kk];
        else if (p == 4) v = Wih1[g * HID + 32 + kk];
        else if (p == 5) v = Whh1[g * HID + kk];
        else             v = Whh1[g * HID + 32 + kk];
        wf[e] = (_Float16)(v * LOG2E);
    }
    // FC A-fragments: row m=0 carries Wfc (TRUE scale), rows 1..15 zero
    for (int e = tid; e < 2 * 64 * 8; e += 512) {
        const int j  = e & 7;
        const int lm = (e >> 3) & 63;
        const int kc = e >> 9;
        const int kk = kc * 32 + (lm >> 4) * 8 + j;
        wfcf[e] = ((lm & 15) == 0) ? (_Float16)Wfc[kk] : (_Float16)0.0f;
    }
    if (tid < 256) bsum1[tid] = (bih1[tid] + bhh1[tid]) * LOG2E;
    __syncthreads();   // the only barrier in the kernel

    _Float16* stW = &state[wave][0];
    const float bfcv = bfc[0];

    // FC fragments hoisted (SSA regs survive the clobber)
    const v8h wfc0 = *(const v8h*)&wfcf[(0 * 64 + lane) * 8];
    const v8h wfc1 = *(const v8h*)&wfcf[(1 * 64 + lane) * 8];

    // z B-fragments for both batch groups (constant over t); element k=16
    // = 1.0 multiplies the (log2e-scaled) bias column staged in plane 0.
    v8h zfa = vzero8(), zfb = vzero8();
    if (q < 2) {
        const float* zpa = z + (size_t)(row0 + c) * LAT + q * 8;
        const float4 a0 = *(const float4*)(zpa);
        const float4 a1 = *(const float4*)(zpa + 4);
        zfa[0] = (_Float16)a0.x; zfa[1] = (_Float16)a0.y;
        zfa[2] = (_Float16)a0.z; zfa[3] = (_Float16)a0.w;
        zfa[4] = (_Float16)a1.x; zfa[5] = (_Float16)a1.y;
        zfa[6] = (_Float16)a1.z; zfa[7] = (_Float16)a1.w;
        const float* zpb = z + (size_t)(row0 + 16 + c) * LAT + q * 8;
        const float4 b0 = *(const float4*)(zpb);
        const float4 b1 = *(const float4*)(zpb + 4);
        zfb[0] = (_Float16)b0.x; zfb[1] = (_Float16)b0.y;
        zfb[2] = (_Float16)b0.z; zfb[3] = (_Float16)b0.w;
        zfb[4] = (_Float16)b1.x; zfb[5] = (_Float16)b1.y;
        zfb[6] = (_Float16)b1.z; zfb[7] = (_Float16)b1.w;
    }
    if (q == 2) { zfa[0] = (_Float16)1.0f; zfb[0] = (_Float16)1.0f; }

    v8h hf0a = vzero8(), hf1a = vzero8();   // h0/x B-frags, group a
    v8h hf0b = vzero8(), hf1b = vzero8();   // group b
    v8h gf0a = vzero8(), gf1a = vzero8();   // h1 B-frags, group a
    v8h gf0b = vzero8(), gf1b = vzero8();   // group b
    v4h h1pka[4], h1pkb[4];                 // packed h1 awaiting deferred write
    float c0s[32], c1s[32];
#pragma unroll
    for (int i = 0; i < 32; ++i) { c0s[i] = 0.0f; c1s[i] = 0.0f; }

#define AFRAG(pl, mt) (*(const v8h*)&wf[(((pl) * 16 + (mt)) * 64 + lane) * 8])
#define MFMA16(A, B, C) __builtin_amdgcn_mfma_f32_16x16x32_f16((A), (B), (C), 0, 0, 0)

    auto l0_part = [&]() {   // L0 MFMAs + epilogue + h0 stores (uses old hf)
#pragma unroll
        for (int a = 0; a < 4; ++a) {
            v4f acc0a[4], acc0b[4];
#pragma unroll
            for (int ty = 0; ty < 4; ++ty) {
                const int mt = 4 * ty + a;
                const v8h A0 = AFRAG(0, mt);
                const v8h A1 = AFRAG(1, mt);
                const v8h A2 = AFRAG(2, mt);
                v4f ta = {0.f, 0.f, 0.f, 0.f};
                v4f tb = {0.f, 0.f, 0.f, 0.f};
                ta = MFMA16(A0, zfa,  ta);  tb = MFMA16(A0, zfb,  tb);
                ta = MFMA16(A1, hf0a, ta);  tb = MFMA16(A1, hf0b, tb);
                ta = MFMA16(A2, hf1a, ta);  tb = MFMA16(A2, hf1b, tb);
                acc0a[ty] = ta; acc0b[ty] = tb;
            }
            float ha[4], hb[4];
#pragma unroll
            for (int r = 0; r < 4; ++r) {
                ha[r] = cell_update(acc0a[0][r], acc0a[1][r], acc0a[2][r],
                                    acc0a[3][r], c0s[a * 4 + r]);
                hb[r] = cell_update(acc0b[0][r], acc0b[1][r], acc0b[2][r],
                                    acc0b[3][r], c0s[16 + a * 4 + r]);
            }
            *(v4h*)&stW[c * 72 + 16 * a + 4 * q] =
                pack4(ha[0], ha[1], ha[2], ha[3]);
            *(v4h*)&stW[(16 + c) * 72 + 16 * a + 4 * q] =
                pack4(hb[0], hb[1], hb[2], hb[3]);
        }
    };

    auto l1_part = [&]() {   // L1 MFMAs + epilogue -> h1pk (uses old hf, gf)
#pragma unroll
        for (int a = 0; a < 4; ++a) {
            v4f acc1a[4], acc1b[4];
#pragma unroll
            for (int ty = 0; ty < 4; ++ty) {
                const int mt = 4 * ty + a;
                const v8h A3 = AFRAG(3, mt);
                const v8h A4 = AFRAG(4, mt);
                const v8h A5 = AFRAG(5, mt);
                const v8h A6 = AFRAG(6, mt);
                v4f ta = *(const v4f*)&bsum1[64 * ty + 16 * a + 4 * q];
                v4f tb = ta;
                ta = MFMA16(A3, hf0a, ta);  tb = MFMA16(A3, hf0b, tb);
                ta = MFMA16(A4, hf1a, ta);  tb = MFMA16(A4, hf1b, tb);
                ta = MFMA16(A5, gf0a, ta);  tb = MFMA16(A5, gf0b, tb);
                ta = MFMA16(A6, gf1a, ta);  tb = MFMA16(A6, gf1b, tb);
                acc1a[ty] = ta; acc1b[ty] = tb;
            }
            float ha[4], hb[4];
#pragma unroll
            for (int r = 0; r < 4; ++r) {
                ha[r] = cell_update(acc1a[0][r], acc1a[1][r], acc1a[2][r],
                                    acc1a[3][r], c1s[a * 4 + r]);
                hb[r] = cell_update(acc1b[0][r], acc1b[1][r], acc1b[2][r],
                                    acc1b[3][r], c1s[16 + a * 4 + r]);
            }
            h1pka[a] = pack4(ha[0], ha[1], ha[2], ha[3]);
            h1pkb[a] = pack4(hb[0], hb[1], hb[2], hb[3]);
        }
    };

    auto l0_finish = [&]() {   // pull new h0 into B-frag registers
        hf0a = *(const v8h*)&stW[c * 72 + 8 * q];
        hf1a = *(const v8h*)&stW[c * 72 + 32 + 8 * q];
        hf0b = *(const v8h*)&stW[(16 + c) * 72 + 8 * q];
        hf1b = *(const v8h*)&stW[(16 + c) * 72 + 32 + 8 * q];
    };

    auto l1_finish = [&](int trow) {   // h1 store, gf reload, FC, out
#pragma unroll
        for (int a = 0; a < 4; ++a) {
            *(v4h*)&stW[c * 72 + 16 * a + 4 * q] = h1pka[a];
            *(v4h*)&stW[(16 + c) * 72 + 16 * a + 4 * q] = h1pkb[a];
        }
        gf0a = *(const v8h*)&stW[c * 72 + 8 * q];
        gf1a = *(const v8h*)&stW[c * 72 + 32 + 8 * q];
        gf0b = *(const v8h*)&stW[(16 + c) * 72 + 8 * q];
        gf1b = *(const v8h*)&stW[(16 + c) * 72 + 32 + 8 * q];
        v4f fa = {0.f, 0.f, 0.f, 0.f};
        v4f fb = {0.f, 0.f, 0.f, 0.f};
        fa = MFMA16(wfc0, gf0a, fa);
        fa = MFMA16(wfc1, gf1a, fa);
        fb = MFMA16(wfc0, gf0b, fb);
        fb = MFMA16(wfc1, gf1b, fb);
        if (lane < 16) {
            out[(size_t)(row0 + lane) * TSTEPS + trow]      = fa[0] + bfcv;
            out[(size_t)(row0 + 16 + lane) * TSTEPS + trow] = fb[0] + bfcv;
        }
    };

    /* --------------------------- pipeline --------------------------- */
    l0_part();          // L0 step 0 (hf, gf are zero)
    l0_finish();

#pragma unroll 1
    for (int tt = 1; tt < TSTEPS; ++tt) {
        // Kill LICM (see header comment). Emits no instructions.
        __asm__ __volatile__("" ::: "memory");
        l0_part();           // writes h0(tt) to stW
        l1_part();           // -> h1pk (registers only)
        l0_finish();         // hf <- h0(tt)
        l1_finish(tt - 1);   // h1 store, gf <- h1(tt-1), FC, out row tt-1
    }

    __asm__ __volatile__("" ::: "memory");
    l1_part();          // L1 step 14
    l1_finish(TSTEPS - 1);

#undef AFRAG
#undef MFMA16
}

extern "C" void kernel_launch(void* const* d_in, const int* in_sizes, int n_in,
                              void* d_out, int out_size, void* d_ws, size_t ws_size,
                              hipStream_t stream)
{
    (void)in_sizes; (void)n_in; (void)out_size; (void)d_ws; (void)ws_size;

    const float* z    = (const float*)d_in[0];
    const float* Wih0 = (const float*)d_in[1];
    const float* Whh0 = (const float*)d_in[2];
    const float* bih0 = (const float*)d_in[3];
    const float* bhh0 = (const float*)d_in[4];
    const float* Wih1 = (const float*)d_in[5];
    const float* Whh1 = (const float*)d_in[6];
    const float* bih1 = (const float*)d_in[7];
    const float* bhh1 = (const float*)d_in[8];
    const float* Wfc  = (const float*)d_in[9];
    const float* bfc  = (const float*)d_in[10];

    lstm2_pipe5<<<dim3(NBATCH / 256), dim3(512), 0, stream>>>(
        z, Wih0, Whh0, bih0, bhh0, Wih1, Whh1, bih1, bhh1, Wfc, bfc,
        (float*)d_out);
}